// Round 9
// baseline (472.523 us; speedup 1.0000x reference)
//
#include <hip/hip_runtime.h>

typedef _Float16 f16;
typedef __attribute__((ext_vector_type(4))) _Float16 f16x4;
typedef __attribute__((ext_vector_type(8))) _Float16 f16x8;
typedef __attribute__((ext_vector_type(4))) float f32x4;
typedef __attribute__((ext_vector_type(16))) float f32x16;

#define DEVI static __device__ __forceinline__

DEVI void async_copy16(const f16* g, f16* l) {
  __builtin_amdgcn_global_load_lds(
      (const __attribute__((address_space(1))) void*)g,
      (__attribute__((address_space(3))) void*)l, 16, 0, 0);
}

#define MEMPIN asm volatile("" ::: "memory")
#define RBAR __builtin_amdgcn_s_barrier()

// ---------------- adjacency: build normalized A, A2=A@A, rowsum(A2) ----------------
__global__ __launch_bounds__(1024) void k_adj(const float* __restrict__ ew, float* __restrict__ out)
{
  __shared__ float sW[62][64];
  __shared__ float sT[62][64];
  __shared__ float d[62];
  const int tid = threadIdx.x;
  for (int idx = tid; idx < 62 * 62; idx += 1024) {
    int i = idx / 62, j = idx % 62;
    float w = (j <= i) ? ew[i * (i + 1) / 2 + j] : ew[j * (j + 1) / 2 + i];
    sW[i][j] = fmaxf(w, 0.f);
  }
  __syncthreads();
  if (tid < 62) {
    float s = 0.f;
    for (int j = 0; j < 62; j++) s += sW[tid][j];
    d[tid] = rsqrtf(s + 1e-10f);
  }
  __syncthreads();
  for (int idx = tid; idx < 62 * 62; idx += 1024) {
    int i = idx / 62, j = idx % 62;
    sW[i][j] *= d[i] * d[j];
  }
  __syncthreads();
  if (tid < 62) {
    float s = 0.f;
    for (int j = 0; j < 62; j++) s += sW[tid][j];
    d[tid] = (s > 0.f) ? rsqrtf(s) : 0.f;
  }
  __syncthreads();
  for (int idx = tid; idx < 62 * 62; idx += 1024) {
    int i = idx / 62, j = idx % 62;
    sW[i][j] *= d[i] * d[j];
  }
  __syncthreads();
  for (int idx = tid; idx < 62 * 64; idx += 1024) {
    int i = idx >> 6, j = idx & 63;
    float s = 0.f;
    if (j < 62) {
      for (int k = 0; k < 62; k++) s += sW[i][k] * sW[k][j];
    }
    sT[i][j] = s;
    out[idx] = s;
  }
  __syncthreads();
  if (tid < 62) {
    float s = 0.f;
    for (int j = 0; j < 62; j++) s += sT[tid][j];
    out[62 * 64 + tid] = s;   // rowsum(A2)
  }
}

// ---------------- BN stats: per-block partial sums, 16 waves/block for TLP ----------------
__global__ __launch_bounds__(1024) void k_bnstats(const float* __restrict__ X, float* __restrict__ part)
{
  const int tid = threadIdx.x;
  const int c4 = (tid & 127) << 2;
  const int rg = tid >> 7;               // 0..7
  float sx = 0, sy = 0, sz = 0, sw = 0, qx = 0, qy = 0, qz = 0, qw = 0;
  const long r0 = (long)blockIdx.x * 496 + rg;
  for (int i = 0; i < 62; i++) {
    const float4 v = *(const float4*)(X + (r0 + 8 * i) * 512 + c4);
    sx += v.x; sy += v.y; sz += v.z; sw += v.w;
    qx += v.x * v.x; qy += v.y * v.y; qz += v.z * v.z; qw += v.w * v.w;
  }
  __shared__ float red[1024][8];
  red[tid][0] = sx; red[tid][1] = sy; red[tid][2] = sz; red[tid][3] = sw;
  red[tid][4] = qx; red[tid][5] = qy; red[tid][6] = qz; red[tid][7] = qw;
  __syncthreads();
  if (tid < 128) {
    float acc8[8];
#pragma unroll
    for (int j = 0; j < 8; j++) acc8[j] = 0.f;
#pragma unroll
    for (int g = 0; g < 8; g++)
#pragma unroll
      for (int j = 0; j < 8; j++) acc8[j] += red[g * 128 + tid][j];
    float* p = part + (long)blockIdx.x * 1024;
#pragma unroll
    for (int j = 0; j < 4; j++) p[c4 + j] = acc8[j];
#pragma unroll
    for (int j = 0; j < 4; j++) p[512 + c4 + j] = acc8[4 + j];
  }
}

__global__ __launch_bounds__(512) void k_bnfin(const float* __restrict__ part, const float* __restrict__ g,
                                               const float* __restrict__ be, float* __restrict__ ssb)
{
  const int c = threadIdx.x;  // 512
  float s = 0.f, q = 0.f;
  for (int b = 0; b < 256; b++) {
    s += part[b * 1024 + c];
    q += part[b * 1024 + 512 + c];
  }
  const float inv = 1.f / 126976.f;
  const float mean = s * inv;
  const float var = q * inv - mean * mean;
  const float sc = g[c] * rsqrtf(var + 1e-5f);
  ssb[c] = sc;
  ssb[512 + c] = be[c] - mean * sc;
}

// ---------------- fold BN scale into lin_w; b1p[h] = sum_f t[f]*W[h][f] ----------------
__global__ __launch_bounds__(256) void k_foldw1(const float* __restrict__ lw, const float* __restrict__ ssb,
                                                f16* __restrict__ w1h, float* __restrict__ b1p)
{
  const int h = blockIdx.x;
  const int tid = threadIdx.x;
  float partl = 0.f;
  for (int f = tid; f < 512; f += 256) {
    const float w = lw[h * 512 + f];
    w1h[h * 512 + f] = (f16)(w * ssb[f]);
    partl += w * ssb[512 + f];
  }
  __shared__ float red[256];
  red[tid] = partl;
  __syncthreads();
  for (int s = 128; s; s >>= 1) {
    if (tid < s) red[tid] += red[tid + s];
    __syncthreads();
  }
  if (tid == 0) b1p[h] = red[0];
}

// ---------------- fp32 -> fp16 weight convert with N/K zero-padding ----------------
DEVI void cvt_body(const float* __restrict__ src, f16* __restrict__ dst,
                   int N, int K, int Npad, int Kpad, int bix, int nblk)
{
  const long total4 = (long)Npad * Kpad / 4;
  const int kp4 = Kpad >> 2;
  for (long i = (long)bix * 256 + threadIdx.x; i < total4; i += (long)nblk * 256) {
    const long n = i / kp4;
    const int k = (int)(i % kp4) << 2;
    f16x4 h;
    if (n < N && k < K) {
      const float4 v = *(const float4*)(src + n * K + k);
      h[0] = (f16)v.x; h[1] = (f16)v.y; h[2] = (f16)v.z; h[3] = (f16)v.w;
    } else {
      h[0] = (f16)0.f; h[1] = (f16)0.f; h[2] = (f16)0.f; h[3] = (f16)0.f;
    }
    *(f16x4*)(dst + i * 4) = h;
  }
}

__global__ __launch_bounds__(256) void k_cvtw(const float* __restrict__ src, f16* __restrict__ dst,
                                              int N, int K, int Npad, int Kpad)
{
  cvt_body(src, dst, N, K, Npad, Kpad, blockIdx.x, gridDim.x);
}

// merged w1+w2 convert: blocks [0,512) -> w1, [512,768) -> w2
__global__ __launch_bounds__(256) void k_cvtw2(const float* __restrict__ s1, f16* __restrict__ d1,
                                               const float* __restrict__ s2, f16* __restrict__ d2)
{
  if (blockIdx.x < 512) cvt_body(s1, d1, 1984, 3968, 2048, 4096, blockIdx.x, 512);
  else                  cvt_body(s2, d2, 992, 1984, 1024, 2048, blockIdx.x - 512, 256);
}

// ---------------- fused lin-GEMM + propagation ----------------
__global__ __launch_bounds__(256, 3) void k_linprop(
    const float* __restrict__ X, const f16* __restrict__ Bw,
    const float* __restrict__ A2, const float* __restrict__ b1p,
    const float* __restrict__ lb, f16* __restrict__ Z)
{
  __shared__ f16 smem[128 * 128];    // [0,16K)=sA  [16K,32K)=sB  -> later yt[128][128]
  __shared__ float sA2[62 * 64];
  __shared__ float sR[62];
  __shared__ float sB1[128];
  __shared__ float sLB[128];
  f16* sA = smem;
  f16* sB = smem + 8192;
  const int tid = threadIdx.x;
  const int lane = tid & 63;
  const int wave = tid >> 6;
  const int wr = wave >> 1, wc = wave & 1;
  const long rowA0 = (long)blockIdx.x * 124;

  for (int i = tid; i < 992; i += 256)
    *(float4*)&sA2[i * 4] = *(const float4*)(A2 + i * 4);
  if (tid < 62) sR[tid] = A2[3968 + tid];
  if (tid < 128) sB1[tid] = b1p[tid];
  if (tid >= 128) sLB[tid - 128] = lb[tid - 128];

  const int srow = tid >> 3;
  const int scolb = (tid & 7) << 4;
  const int gcolb = scolb ^ ((srow & 7) << 4);
  const f16* gB = Bw + (long)srow * 512 + (gcolb >> 1);
  f16* lB = sB + srow * 64 + (scolb >> 1);

  const int ac4 = tid & 15;
  const int ar0 = tid >> 4;
  const int aswz = (ar0 & 7) << 4;
  char* lAbase = (char*)sA + ar0 * 128 + ((ac4 * 8) ^ aswz);

  const int frow = lane & 15;
  const int kb = (lane >> 4) << 4;
  const int rswz = (lane & 7) << 4;

  f32x4 acc[4][4] = {};

  for (int kt = 0; kt < 512; kt += 64) {
#pragma unroll
    for (int i = 0; i < 8; i++) {
      long rr = rowA0 + ar0 + 16 * i;
      if (rr > 126975) rr = 126975;          // clamp (last block reads dup row; outputs unused)
      const float4 v = *(const float4*)(X + rr * 512 + kt + ac4 * 4);
      f16x4 hh;
      hh[0] = (f16)v.x; hh[1] = (f16)v.y; hh[2] = (f16)v.z; hh[3] = (f16)v.w;
      *(f16x4*)(lAbase + 16 * i * 128) = hh;
    }
#pragma unroll
    for (int i = 0; i < 4; i++)
      async_copy16(gB + kt + (long)i * (32 * 512), lB + i * 2048);
    __syncthreads();
#pragma unroll
    for (int kk = 0; kk < 2; kk++) {
      f16x8 af[4], bf[4];
#pragma unroll
      for (int m = 0; m < 4; m++) {
        const int row = wr * 64 + m * 16 + frow;
        af[m] = *(const f16x8*)((const char*)sA + row * 128 + ((kk * 64 + kb) ^ rswz));
      }
#pragma unroll
      for (int n = 0; n < 4; n++) {
        const int row = wc * 64 + n * 16 + frow;
        bf[n] = *(const f16x8*)((const char*)sB + row * 128 + ((kk * 64 + kb) ^ rswz));
      }
#pragma unroll
      for (int m = 0; m < 4; m++)
#pragma unroll
        for (int n = 0; n < 4; n++)
          acc[m][n] = __builtin_amdgcn_mfma_f32_16x16x32_f16(af[m], bf[n], acc[m][n], 0, 0, 0);
    }
    __syncthreads();
  }

  // write Y-tile (f16) into the dead staging LDS
  const int crow = wr * 64 + ((lane >> 4) << 2);
  const int ccol = wc * 64 + (lane & 15);
#pragma unroll
  for (int n = 0; n < 4; n++)
#pragma unroll
    for (int m = 0; m < 4; m++)
#pragma unroll
      for (int r = 0; r < 4; r++)
        smem[(crow + m * 16 + r) * 128 + ccol + n * 16] = (f16)acc[m][n][r];
  __syncthreads();

  // propagation: thread = (batch g, channel h)
  const int h = tid & 127;
  const int g = tid >> 7;
  float yc[62];
#pragma unroll
  for (int j = 0; j < 62; j++) yc[j] = (float)smem[(g * 62 + j) * 128 + h];
  const float bh1 = sB1[h];
  const float bh2 = sLB[h];
  f16* zp = Z + ((long)blockIdx.x * 2 + g) * 7936 + h;
  for (int n = 0; n < 62; n++) {
    float s = 0.f;
#pragma unroll
    for (int j = 0; j < 62; j++) s += sA2[n * 64 + j] * yc[j];
    zp[n * 128] = (f16)(s + sR[n] * bh1 + bh2);
  }
}

// ---------------- 256x256-tile pipelined GEMM, split-K, f16 partials, 32x32x16 MFMA ----------------
// Round-6 schedule (proven fastest at 1 block/CU): bunched reads at the LDS-traffic floor
// (24 b128/wave/K-tile, each fragment once), 6 barriers per 2-K-tile iteration, counted
// vmcnt(8). MFMA = 32x32x16_f16 (2495 TF ubench vs 2075 for 16x16 -> -17% matrix-pipe time,
// half the instructions). Fragments: A/B lane row = lane&31, k = 8*(lane>>5)+j (16B chunk);
// C/D row = (r&3)+8*(r>>2)+4*(lane>>5), col = lane&31. VGPR footprint identical to 16x16 ver.
template <int LOOPN, int MT, int NT, int KS>
__global__ __launch_bounds__(512, 2) void k_fc8(
    const f16* __restrict__ A, const f16* __restrict__ Bw, f16* __restrict__ P,
    const int K, const int kslice, const int PLD)
{
  __shared__ f16 sA[2][256 * 64];
  __shared__ f16 sB[2][256 * 64];
  const int tid = threadIdx.x;
  const int bid = blockIdx.x;
  const int xcd = bid & 7, ii = bid >> 3;
  int nt, mt, ks;
  if constexpr (NT == 16) {
    nt = xcd * 2 + (ii & 1); mt = (ii >> 1) & (MT - 1); ks = ii >> 4;
  } else {  // NT == 8
    nt = xcd; mt = ii & (MT - 1); ks = ii >> 3;
  }
  const long rowA0 = (long)mt * 256;
  const long rowB0 = (long)nt * 256;
  const long k0 = (long)ks * kslice;

  const int srow = tid >> 3;             // 0..63
  const int scolb = (tid & 7) << 4;      // LDS byte col 0..112
  const int gcolb = scolb ^ ((srow & 7) << 4);  // pre-swizzled source col
  const f16* gA = A + (rowA0 + srow) * (long)K + k0 + (gcolb >> 1);
  const f16* gB = Bw + (rowB0 + srow) * (long)K + k0 + (gcolb >> 1);

#define SGA(d, q, kt) async_copy16(gA + (kt) + (long)(q) * 64 * K, &sA[d][0] + (q) * 4096 + tid * 8)
#define SGB(d, q, kt) async_copy16(gB + (kt) + (long)(q) * 64 * K, &sB[d][0] + (q) * 4096 + tid * 8)

  const int lane = tid & 63;
  const int wave = tid >> 6;
  const int wr = wave >> 2;              // 0..1  (128-row half)
  const int wc = wave & 3;               // 0..3  (64-col quarter)
  const int r31 = lane & 31;
  const int hi16 = (lane >> 5) << 4;     // k-chunk byte offset within k-step
  const int rsw = (lane & 7) << 4;       // swizzle (row&7 == lane&7 for our rows)

  f32x16 acc[4][2] = {};                 // [m4 frag 0..3][n2 frag 0..1]
  f16x8 af[2][4], bf[2][4];              // [frag][kstep]

#define RDA(d, mh) do { _Pragma("unroll") for (int m_ = 0; m_ < 2; m_++) {                      \
    const int row_ = wr * 128 + (mh) * 64 + m_ * 32 + r31;                                      \
    _Pragma("unroll") for (int ks_ = 0; ks_ < 4; ks_++)                                         \
      af[m_][ks_] = *(const f16x8*)((const char*)&sA[d][0] + row_ * 128 + ((ks_ * 32 + hi16) ^ rsw)); } } while (0)
#define RDB(d) do { _Pragma("unroll") for (int n_ = 0; n_ < 2; n_++) {                          \
    const int row_ = wc * 64 + n_ * 32 + r31;                                                   \
    _Pragma("unroll") for (int ks_ = 0; ks_ < 4; ks_++)                                         \
      bf[n_][ks_] = *(const f16x8*)((const char*)&sB[d][0] + row_ * 128 + ((ks_ * 32 + hi16) ^ rsw)); } } while (0)
#define QUAD(mh, nh) do { _Pragma("unroll") for (int ks_ = 0; ks_ < 4; ks_++)                   \
    _Pragma("unroll") for (int m_ = 0; m_ < 2; m_++)                                            \
      acc[(mh)*2+m_][nh] = __builtin_amdgcn_mfma_f32_32x32x16_f16(af[m_][ks_], bf[nh][ks_], acc[(mh)*2+m_][nh], 0, 0, 0); } while (0)
#define VMW8 asm volatile("s_waitcnt vmcnt(8)" ::: "memory")
#define VMW0 asm volatile("s_waitcnt vmcnt(0)" ::: "memory")
#define PRIO1 __builtin_amdgcn_s_setprio(1)
#define PRIO0 __builtin_amdgcn_s_setprio(0)

  // prologue: tile0 -> d0, tile1 -> d1
  SGA(0, 0, 0); SGA(0, 2, 0); SGB(0, 0, 0); SGB(0, 1, 0);
  SGA(0, 1, 0); SGA(0, 3, 0); SGB(0, 2, 0); SGB(0, 3, 0);
  SGA(1, 0, 64); SGA(1, 2, 64); SGB(1, 0, 64); SGB(1, 1, 64);
  SGA(1, 1, 64); SGA(1, 3, 64); SGB(1, 2, 64); SGB(1, 3, 64);

  for (int t = 0; t < LOOPN; ++t) {
    const long kt2 = (long)(t + 1) * 128;   // rel K offset of tile 2t+2
    // P0: compute d0 quad(0,0)
    VMW8; MEMPIN; RBAR; MEMPIN;
    RDA(0, 0); RDB(0);
    PRIO1; QUAD(0, 0); PRIO0;
    MEMPIN; RBAR; MEMPIN;
    // P1: stage tile(2t+2) A02,B01 -> d0
    SGA(0, 0, kt2); SGA(0, 2, kt2); SGB(0, 0, kt2); SGB(0, 1, kt2);
    QUAD(0, 1);
    // P2
    RDA(0, 1);
    QUAD(1, 0);
    MEMPIN; RBAR; MEMPIN;
    // P3: stage tile(2t+2) A13,B23 -> d0
    SGA(0, 1, kt2); SGA(0, 3, kt2); SGB(0, 2, kt2); SGB(0, 3, kt2);
    QUAD(1, 1);
    // P4: compute d1 quad(0,0)
    VMW8; MEMPIN; RBAR; MEMPIN;
    RDA(1, 0); RDB(1);
    PRIO1; QUAD(0, 0); PRIO0;
    MEMPIN; RBAR; MEMPIN;
    // P5: stage tile(2t+3) A02,B01 -> d1
    SGA(1, 0, kt2 + 64); SGA(1, 2, kt2 + 64); SGB(1, 0, kt2 + 64); SGB(1, 1, kt2 + 64);
    QUAD(0, 1);
    // P6
    RDA(1, 1);
    QUAD(1, 0);
    MEMPIN; RBAR; MEMPIN;
    // P7: stage tile(2t+3) A13,B23 -> d1
    SGA(1, 1, kt2 + 64); SGA(1, 3, kt2 + 64); SGB(1, 2, kt2 + 64); SGB(1, 3, kt2 + 64);
    QUAD(1, 1);
  }
  // peeled final iteration: last two tiles
  VMW8; MEMPIN; RBAR; MEMPIN;
  RDA(0, 0); RDB(0);
  PRIO1; QUAD(0, 0); QUAD(0, 1); PRIO0;
  RDA(0, 1);
  PRIO1; QUAD(1, 0); QUAD(1, 1); PRIO0;
  VMW0; MEMPIN; RBAR; MEMPIN;
  RDA(1, 0); RDB(1);
  PRIO1; QUAD(0, 0); QUAD(0, 1); PRIO0;
  RDA(1, 1);
  PRIO1; QUAD(1, 0); QUAD(1, 1); PRIO0;

  // epilogue: write f16 partial P[ks][2048][PLD]; C/D: row=(r&3)+8*(r>>2)+4*(lane>>5), col=lane&31
  f16* Pp = P + (long)ks * 2048 * PLD;
#pragma unroll
  for (int mi = 0; mi < 4; mi++) {
    const long rbase = rowA0 + wr * 128 + mi * 32 + 4 * (lane >> 5);
#pragma unroll
    for (int nh = 0; nh < 2; nh++) {
      const long col = rowB0 + wc * 64 + nh * 32 + r31;
#pragma unroll
      for (int r = 0; r < 16; r++) {
        const long row = rbase + (r & 3) + 8 * (r >> 2);
        Pp[row * PLD + col] = (f16)acc[mi][nh][r];
      }
    }
  }
#undef SGA
#undef SGB
#undef RDA
#undef RDB
#undef QUAD
#undef VMW8
#undef VMW0
#undef PRIO1
#undef PRIO0
}

// ---------------- fixup: C = relu(sum_s P_s + b) ----------------
template <int S>
__global__ __launch_bounds__(256) void k_fixs(const f16* __restrict__ P, const float* __restrict__ b,
                                              f16* __restrict__ C, int N, int realN)
{
  const long total = 2048L * N;
  const int mask = N - 1;
  const long stride = (long)gridDim.x * 256 * 8;
  for (long i = ((long)blockIdx.x * 256 + threadIdx.x) * 8; i < total; i += stride) {
    float s[8];
#pragma unroll
    for (int j = 0; j < 8; j++) s[j] = 0.f;
#pragma unroll
    for (int ps = 0; ps < S; ps++) {
      const f16x8 p = *(const f16x8*)(P + (long)ps * total + i);
#pragma unroll
      for (int j = 0; j < 8; j++) s[j] += (float)p[j];
    }
    const int col = (int)(i & mask);
    f16x8 o;
#pragma unroll
    for (int j = 0; j < 8; j++) {
      const int c = col + j;
      const float bb = (c < realN) ? b[c] : 0.f;
      o[j] = (f16)fmaxf(s[j] + bb, 0.f);
    }
    *(f16x8*)(C + i) = o;
  }
}

// ---------------- generic fp16 BT GEMM (128x128), 1D grid + XCD decode ----------------
// KS=1: C = act(A@B^T + bias). KS=2: split-K, writes f16 partials to C (=P), no bias/act.
template <int RELU, int KS>
__global__ __launch_bounds__(256, 2) void k_gemm_f16(
    const f16* __restrict__ A, const f16* __restrict__ B,
    const float* __restrict__ bias, f16* __restrict__ C,
    int N, int K, int realN)
{
  __shared__ f16 sA[128 * 64];
  __shared__ f16 sB[128 * 64];
  const int tid = threadIdx.x;
  const int lane = tid & 63;
  const int wave = tid >> 6;
  const int wr = wave >> 1, wc = wave & 1;
  const int bid = blockIdx.x;
  const int xcd = bid & 7, idx = bid >> 3;
  const long rowA0 = (long)(xcd * 2 + (idx & 1)) * 128;
  long rowB0;
  int ks;
  if constexpr (KS == 2) {
    rowB0 = (long)((idx >> 1) & 7) * 128;
    ks = idx >> 4;
  } else {
    rowB0 = (long)(idx >> 1) * 128;
    ks = 0;
  }
  const int kslice = K / KS;
  const long k0 = (long)ks * kslice;

  const int srow = tid >> 3;
  const int scolb = (tid & 7) << 4;
  const int gcolb = scolb ^ ((srow & 7) << 4);
  const f16* gA = A + (rowA0 + srow) * (long)K + k0 + (gcolb >> 1);
  const f16* gB = B + (rowB0 + srow) * (long)K + k0 + (gcolb >> 1);
  f16* lA = sA + srow * 64 + (scolb >> 1);
  f16* lB = sB + srow * 64 + (scolb >> 1);
  const long rstep = 32L * K;

  const int frow = lane & 15;
  const int kb = (lane >> 4) << 4;
  const int rswz = (lane & 7) << 4;

  f32x4 acc[4][4] = {};

  for (int kt = 0; kt < kslice; kt += 64) {
#pragma unroll
    for (int i = 0; i < 4; i++) {
      async_copy16(gA + kt + i * rstep, lA + i * 2048);
      async_copy16(gB + kt + i * rstep, lB + i * 2048);
    }
    __syncthreads();
#pragma unroll
    for (int kk = 0; kk < 2; kk++) {
      f16x8 af[4], bf[4];
#pragma unroll
      for (int m = 0; m < 4; m++) {
        const int row = wr * 64 + m * 16 + frow;
        af[m] = *(const f16x8*)((const char*)sA + row * 128 + ((kk * 64 + kb) ^ rswz));
      }
#pragma unroll
      for (int n = 0; n < 4; n++) {
        const int row = wc * 64 + n * 16 + frow;
        bf[n] = *(const f16x8*)((const char*)sB + row * 128 + ((kk * 64 + kb) ^ rswz));
      }
#pragma unroll
      for (int m = 0; m < 4; m++)
#pragma unroll
        for (int n = 0; n < 4; n++)
          acc[m][n] = __builtin_amdgcn_mfma_f32_16x16x32_f16(af[m], bf[n], acc[m][n], 0, 0, 0);
    }
    __syncthreads();
  }

  const int crow = wr * 64 + ((lane >> 4) << 2);
  const int ccol = wc * 64 + (lane & 15);
  if constexpr (KS == 1) {
#pragma unroll
    for (int n = 0; n < 4; n++) {
      const int col = (int)rowB0 + ccol + n * 16;
      const float bb = (col < realN) ? bias[col] : 0.f;
#pragma unroll
      for (int m = 0; m < 4; m++) {
        const long gr = rowA0 + crow + m * 16;
#pragma unroll
        for (int r = 0; r < 4; r++) {
          float v = acc[m][n][r] + bb;
          if (RELU) v = fmaxf(v, 0.f);
          C[(gr + r) * N + col] = (f16)v;
        }
      }
    }
  } else {
    f16* Pp = C + (long)ks * 2048 * N;
#pragma unroll
    for (int n = 0; n < 4; n++) {
      const long col = rowB0 + ccol + n * 16;
#pragma unroll
      for (int m = 0; m < 4; m++) {
        const long gr = rowA0 + crow + m * 16;
#pragma unroll
        for (int r = 0; r < 4; r++)
          Pp[(gr + r) * N + col] = (f16)acc[m][n][r];
      }
    }
  }
}

// ---------------- fc3: out[2048,2] = h2[:, :992] @ w3^T + b3 ----------------
__global__ __launch_bounds__(256) void k_fc3(const f16* __restrict__ H, const float* __restrict__ W,
                                             const float* __restrict__ b, float* __restrict__ out)
{
  const int row = blockIdx.x * 4 + (threadIdx.x >> 6);
  const int lane = threadIdx.x & 63;
  const f16* h = H + (long)row * 1024;
  float a0 = 0.f, a1 = 0.f;
  for (int k = lane; k < 992; k += 64) {
    const float v = (float)h[k];
    a0 += v * W[k];
    a1 += v * W[992 + k];
  }
  for (int off = 32; off; off >>= 1) {
    a0 += __shfl_down(a0, off);
    a1 += __shfl_down(a1, off);
  }
  if (lane == 0) {
    out[row * 2 + 0] = a0 + b[0];
    out[row * 2 + 1] = a1 + b[1];
  }
}

extern "C" void kernel_launch(void* const* d_in, const int* in_sizes, int n_in,
                              void* d_out, int out_size, void* d_ws, size_t ws_size,
                              hipStream_t stream)
{
  const float* x    = (const float*)d_in[0];
  const float* ew   = (const float*)d_in[1];
  const float* bng  = (const float*)d_in[2];
  const float* bnb  = (const float*)d_in[3];
  const float* linw = (const float*)d_in[4];
  const float* linb = (const float*)d_in[5];
  const float* w0   = (const float*)d_in[6];
  const float* b0   = (const float*)d_in[7];
  const float* w1   = (const float*)d_in[8];
  const float* b1   = (const float*)d_in[9];
  const float* w2   = (const float*)d_in[10];
  const float* b2   = (const float*)d_in[11];
  const float* w3   = (const float*)d_in[12];
  const float* b3   = (const float*)d_in[13];
  float* out = (float*)d_out;
  char* ws = (char*)d_ws;

  // layout (bytes)
  constexpr size_t oA2  = 0;                         // 16384
  constexpr size_t oSS  = 16384;                     // 4096
  constexpr size_t oB1P = 20480;                     // 512
  constexpr size_t oW1H = 20992;                     // 131072, end 152064
  constexpr size_t oP   = 152064;                    // 33554432 (fc0: 2x2048x4096; fc1: 4x2048x2048; fc2: 2x2048x1024 f16)
  constexpr size_t oACC = oP;                        // bn partials (1 MiB), dead before fc0
  constexpr size_t oZ   = 33706496;                  // 32505856, end 66212352
  constexpr size_t oW0H = 66212352;                  // 4096*7936 f16 = 65011712, end 131224064
  constexpr size_t WS_NEED = 131224064;
  // post-fc0 aliases (Z and w0h dead after fc0):
  constexpr size_t oH0  = oZ;                        // 2048*4096 f16 = 16777216
  constexpr size_t oW1F = oZ + 16777216;             // 16777216, end 67260928
  constexpr size_t oH1  = 67260928;                  // 8388608
  constexpr size_t oW2F = 75649536;                  // 4194304
  constexpr size_t oH2  = 79843840;                  // 4194304
  if (ws_size < WS_NEED) return;

  float* A2  = (float*)(ws + oA2);
  float* acc = (float*)(ws + oACC);
  float* ssb = (float*)(ws + oSS);
  float* b1p = (float*)(ws + oB1P);
  f16* w1h = (f16*)(ws + oW1H);
  f16* P   = (f16*)(ws + oP);
  f16* Z   = (f16*)(ws + oZ);
  f16* w0h = (f16*)(ws + oW0H);
  f16* h0  = (f16*)(ws + oH0);
  f16* w1f = (f16*)(ws + oW1F);
  f16* h1  = (f16*)(ws + oH1);
  f16* w2f = (f16*)(ws + oW2F);
  f16* h2  = (f16*)(ws + oH2);

  k_adj<<<1, 1024, 0, stream>>>(ew, A2);
  k_bnstats<<<256, 1024, 0, stream>>>(x, acc);
  k_bnfin<<<1, 512, 0, stream>>>(acc, bng, bnb, ssb);
  k_foldw1<<<128, 256, 0, stream>>>(linw, ssb, w1h, b1p);
  k_cvtw<<<1024, 256, 0, stream>>>(w0, w0h, 3968, 7936, 4096, 7936);
  // fused lin-GEMM + 2-hop propagation -> Z
  k_linprop<<<1024, 256, 0, stream>>>(x, w1h, A2, b1p, linb, Z);
  // fc0: [2048,7936] x [4096(3968),7936]^T -> f16 partials (split-K=2), then fixup
  k_fc8<30, 8, 16, 2><<<256, 512, 0, stream>>>(Z, w0h, P, 7936, 3968, 4096);
  k_fixs<2><<<2048, 256, 0, stream>>>(P, b0, h0, 4096, 3968);
  // convert fc1/fc2 weights into dead Z/w0h space (merged launch)
  k_cvtw2<<<768, 256, 0, stream>>>(w1, w1f, w2, w2f);
  // fc1: [2048,4096] x [2048(1984),4096]^T -> f16 partials (split-K=4), then fixup
  k_fc8<7, 8, 8, 4><<<256, 512, 0, stream>>>(h0, w1f, P, 4096, 1024, 2048);
  k_fixs<4><<<1024, 256, 0, stream>>>(P, b1, h1, 2048, 1984);
  // fc2: [2048,2048] x [1024(992),2048]^T -> split-K=2 partials (256 blocks), then fixup
  k_gemm_f16<1, 2><<<256, 256, 0, stream>>>(h1, w2f, b2, P, 1024, 2048, 992);
  k_fixs<2><<<512, 256, 0, stream>>>(P, b2, h2, 1024, 992);
  k_fc3<<<512, 256, 0, stream>>>(h2, w3, b3, out);
}

// Round 11
// 408.798 us; speedup vs baseline: 1.1559x; 1.1559x over previous
//
#include <hip/hip_runtime.h>

typedef _Float16 f16;
typedef __attribute__((ext_vector_type(4))) _Float16 f16x4;
typedef __attribute__((ext_vector_type(8))) _Float16 f16x8;
typedef __attribute__((ext_vector_type(4))) float f32x4;

#define DEVI static __device__ __forceinline__

DEVI void async_copy16(const f16* g, f16* l) {
  __builtin_amdgcn_global_load_lds(
      (const __attribute__((address_space(1))) void*)g,
      (__attribute__((address_space(3))) void*)l, 16, 0, 0);
}

#define MEMPIN asm volatile("" ::: "memory")
#define RBAR __builtin_amdgcn_s_barrier()

// ---------------- merged BN-stats (blocks 0..255) + adjacency build (block 256) ----------------
__global__ __launch_bounds__(1024) void k_bnadj(const float* __restrict__ X, float* __restrict__ part,
                                                const float* __restrict__ ew, float* __restrict__ A2out)
{
  __shared__ float red[1024][8];     // bnstats
  __shared__ float sW[62][64];       // adj
  __shared__ float sT[62][64];
  __shared__ float d[62];
  const int tid = threadIdx.x;

  if (blockIdx.x < 256) {
    // ---- BN stats: per-block partial sums, 16 waves for TLP ----
    const int c4 = (tid & 127) << 2;
    const int rg = tid >> 7;
    float sx = 0, sy = 0, sz = 0, sw = 0, qx = 0, qy = 0, qz = 0, qw = 0;
    const long r0 = (long)blockIdx.x * 496 + rg;
    for (int i = 0; i < 62; i++) {
      const float4 v = *(const float4*)(X + (r0 + 8 * i) * 512 + c4);
      sx += v.x; sy += v.y; sz += v.z; sw += v.w;
      qx += v.x * v.x; qy += v.y * v.y; qz += v.z * v.z; qw += v.w * v.w;
    }
    red[tid][0] = sx; red[tid][1] = sy; red[tid][2] = sz; red[tid][3] = sw;
    red[tid][4] = qx; red[tid][5] = qy; red[tid][6] = qz; red[tid][7] = qw;
    __syncthreads();
    if (tid < 128) {
      float acc8[8];
#pragma unroll
      for (int j = 0; j < 8; j++) acc8[j] = 0.f;
#pragma unroll
      for (int g = 0; g < 8; g++)
#pragma unroll
        for (int j = 0; j < 8; j++) acc8[j] += red[g * 128 + tid][j];
      float* p = part + (long)blockIdx.x * 1024;
#pragma unroll
      for (int j = 0; j < 4; j++) p[c4 + j] = acc8[j];
#pragma unroll
      for (int j = 0; j < 4; j++) p[512 + c4 + j] = acc8[4 + j];
    }
    return;
  }

  // ---- adjacency: normalized A, A2=A@A, rowsum(A2) ----
  for (int idx = tid; idx < 62 * 62; idx += 1024) {
    int i = idx / 62, j = idx % 62;
    float w = (j <= i) ? ew[i * (i + 1) / 2 + j] : ew[j * (j + 1) / 2 + i];
    sW[i][j] = fmaxf(w, 0.f);
  }
  __syncthreads();
  if (tid < 62) {
    float s = 0.f;
    for (int j = 0; j < 62; j++) s += sW[tid][j];
    d[tid] = rsqrtf(s + 1e-10f);
  }
  __syncthreads();
  for (int idx = tid; idx < 62 * 62; idx += 1024) {
    int i = idx / 62, j = idx % 62;
    sW[i][j] *= d[i] * d[j];
  }
  __syncthreads();
  if (tid < 62) {
    float s = 0.f;
    for (int j = 0; j < 62; j++) s += sW[tid][j];
    d[tid] = (s > 0.f) ? rsqrtf(s) : 0.f;
  }
  __syncthreads();
  for (int idx = tid; idx < 62 * 62; idx += 1024) {
    int i = idx / 62, j = idx % 62;
    sW[i][j] *= d[i] * d[j];
  }
  __syncthreads();
  for (int idx = tid; idx < 62 * 64; idx += 1024) {
    int i = idx >> 6, j = idx & 63;
    float s = 0.f;
    if (j < 62) {
      for (int k = 0; k < 62; k++) s += sW[i][k] * sW[k][j];
    }
    sT[i][j] = s;
    A2out[idx] = s;
  }
  __syncthreads();
  if (tid < 62) {
    float s = 0.f;
    for (int j = 0; j < 62; j++) s += sT[tid][j];
    A2out[62 * 64 + tid] = s;   // rowsum(A2)
  }
}

__global__ __launch_bounds__(512) void k_bnfin(const float* __restrict__ part, const float* __restrict__ g,
                                               const float* __restrict__ be, float* __restrict__ ssb)
{
  const int c = threadIdx.x;  // 512
  float s = 0.f, q = 0.f;
  for (int b = 0; b < 256; b++) {
    s += part[b * 1024 + c];
    q += part[b * 1024 + 512 + c];
  }
  const float inv = 1.f / 126976.f;
  const float mean = s * inv;
  const float var = q * inv - mean * mean;
  const float sc = g[c] * rsqrtf(var + 1e-5f);
  ssb[c] = sc;
  ssb[512 + c] = be[c] - mean * sc;
}

// ---------------- fold BN scale into lin_w; b1p[h] = sum_f t[f]*W[h][f] ----------------
__global__ __launch_bounds__(256) void k_foldw1(const float* __restrict__ lw, const float* __restrict__ ssb,
                                                f16* __restrict__ w1h, float* __restrict__ b1p)
{
  const int h = blockIdx.x;
  const int tid = threadIdx.x;
  float partl = 0.f;
  for (int f = tid; f < 512; f += 256) {
    const float w = lw[h * 512 + f];
    w1h[h * 512 + f] = (f16)(w * ssb[f]);
    partl += w * ssb[512 + f];
  }
  __shared__ float red[256];
  red[tid] = partl;
  __syncthreads();
  for (int s = 128; s; s >>= 1) {
    if (tid < s) red[tid] += red[tid + s];
    __syncthreads();
  }
  if (tid == 0) b1p[h] = red[0];
}

// ---------------- fp32 -> fp16 weight convert with N/K zero-padding ----------------
DEVI void cvt_body(const float* __restrict__ src, f16* __restrict__ dst,
                   int N, int K, int Npad, int Kpad, int bix, int nblk)
{
  const long total4 = (long)Npad * Kpad / 4;
  const int kp4 = Kpad >> 2;
  for (long i = (long)bix * 256 + threadIdx.x; i < total4; i += (long)nblk * 256) {
    const long n = i / kp4;
    const int k = (int)(i % kp4) << 2;
    f16x4 h;
    if (n < N && k < K) {
      const float4 v = *(const float4*)(src + n * K + k);
      h[0] = (f16)v.x; h[1] = (f16)v.y; h[2] = (f16)v.z; h[3] = (f16)v.w;
    } else {
      h[0] = (f16)0.f; h[1] = (f16)0.f; h[2] = (f16)0.f; h[3] = (f16)0.f;
    }
    *(f16x4*)(dst + i * 4) = h;
  }
}

// ---------------- merged fused lin-GEMM+prop (blocks 0..1023) + w0 convert (1024..2047) ----------------
__global__ __launch_bounds__(256, 3) void k_linprop_cvt(
    const float* __restrict__ X, const f16* __restrict__ Bw,
    const float* __restrict__ A2, const float* __restrict__ b1p,
    const float* __restrict__ lb, f16* __restrict__ Z,
    const float* __restrict__ w0, f16* __restrict__ w0h)
{
  __shared__ f16 smem[128 * 128];    // [0,16K)=sA  [16K,32K)=sB  -> later yt[128][128]
  __shared__ float sA2[62 * 64];
  __shared__ float sR[62];
  __shared__ float sB1[128];
  __shared__ float sLB[128];

  if (blockIdx.x >= 1024) {          // w0 fp32->f16 convert with N-pad to 4096
    cvt_body(w0, w0h, 3968, 7936, 4096, 7936, blockIdx.x - 1024, 1024);
    return;
  }

  f16* sA = smem;
  f16* sB = smem + 8192;
  const int tid = threadIdx.x;
  const int lane = tid & 63;
  const int wave = tid >> 6;
  const int wr = wave >> 1, wc = wave & 1;
  const long rowA0 = (long)blockIdx.x * 124;

  for (int i = tid; i < 992; i += 256)
    *(float4*)&sA2[i * 4] = *(const float4*)(A2 + i * 4);
  if (tid < 62) sR[tid] = A2[3968 + tid];
  if (tid < 128) sB1[tid] = b1p[tid];
  if (tid >= 128) sLB[tid - 128] = lb[tid - 128];

  const int srow = tid >> 3;
  const int scolb = (tid & 7) << 4;
  const int gcolb = scolb ^ ((srow & 7) << 4);
  const f16* gB = Bw + (long)srow * 512 + (gcolb >> 1);
  f16* lB = sB + srow * 64 + (scolb >> 1);

  const int ac4 = tid & 15;
  const int ar0 = tid >> 4;
  const int aswz = (ar0 & 7) << 4;
  char* lAbase = (char*)sA + ar0 * 128 + ((ac4 * 8) ^ aswz);

  const int frow = lane & 15;
  const int kb = (lane >> 4) << 4;
  const int rswz = (lane & 7) << 4;

  f32x4 acc[4][4] = {};

  for (int kt = 0; kt < 512; kt += 64) {
#pragma unroll
    for (int i = 0; i < 8; i++) {
      long rr = rowA0 + ar0 + 16 * i;
      if (rr > 126975) rr = 126975;          // clamp (last block reads dup row; outputs unused)
      const float4 v = *(const float4*)(X + rr * 512 + kt + ac4 * 4);
      f16x4 hh;
      hh[0] = (f16)v.x; hh[1] = (f16)v.y; hh[2] = (f16)v.z; hh[3] = (f16)v.w;
      *(f16x4*)(lAbase + 16 * i * 128) = hh;
    }
#pragma unroll
    for (int i = 0; i < 4; i++)
      async_copy16(gB + kt + (long)i * (32 * 512), lB + i * 2048);
    __syncthreads();
#pragma unroll
    for (int kk = 0; kk < 2; kk++) {
      f16x8 af[4], bf[4];
#pragma unroll
      for (int m = 0; m < 4; m++) {
        const int row = wr * 64 + m * 16 + frow;
        af[m] = *(const f16x8*)((const char*)sA + row * 128 + ((kk * 64 + kb) ^ rswz));
      }
#pragma unroll
      for (int n = 0; n < 4; n++) {
        const int row = wc * 64 + n * 16 + frow;
        bf[n] = *(const f16x8*)((const char*)sB + row * 128 + ((kk * 64 + kb) ^ rswz));
      }
#pragma unroll
      for (int m = 0; m < 4; m++)
#pragma unroll
        for (int n = 0; n < 4; n++)
          acc[m][n] = __builtin_amdgcn_mfma_f32_16x16x32_f16(af[m], bf[n], acc[m][n], 0, 0, 0);
    }
    __syncthreads();
  }

  // write Y-tile (f16) into the dead staging LDS
  const int crow = wr * 64 + ((lane >> 4) << 2);
  const int ccol = wc * 64 + (lane & 15);
#pragma unroll
  for (int n = 0; n < 4; n++)
#pragma unroll
    for (int m = 0; m < 4; m++)
#pragma unroll
      for (int r = 0; r < 4; r++)
        smem[(crow + m * 16 + r) * 128 + ccol + n * 16] = (f16)acc[m][n][r];
  __syncthreads();

  // propagation: thread = (batch g, channel h)
  const int h = tid & 127;
  const int g = tid >> 7;
  float yc[62];
#pragma unroll
  for (int j = 0; j < 62; j++) yc[j] = (float)smem[(g * 62 + j) * 128 + h];
  const float bh1 = sB1[h];
  const float bh2 = sLB[h];
  f16* zp = Z + ((long)blockIdx.x * 2 + g) * 7936 + h;
  for (int n = 0; n < 62; n++) {
    float s = 0.f;
#pragma unroll
    for (int j = 0; j < 62; j++) s += sA2[n * 64 + j] * yc[j];
    zp[n * 128] = (f16)(s + sR[n] * bh1 + bh2);
  }
}

// ---------------- 256x256-tile 8-phase pipelined GEMM, split-K, f16 partials ----------------
// Round-6 schedule (proven fastest at 1 block/CU, 16x16x32 MFMA): bunched reads at the
// LDS-traffic floor (24 b128/wave/K-tile, each fragment once), 6 barriers per 2-K-tile
// iteration, counted vmcnt(8). Failed variants: fine 16-barrier interleave (r5 +16us,
// r7 +11us), 32x32x16 MFMA (r9: 1.2e7 LDS bank conflicts, +8us).
template <int LOOPN, int MT, int NT, int KS>
__global__ __launch_bounds__(512, 2) void k_fc8(
    const f16* __restrict__ A, const f16* __restrict__ Bw, f16* __restrict__ P,
    const int K, const int kslice, const int PLD)
{
  __shared__ f16 sA[2][256 * 64];
  __shared__ f16 sB[2][256 * 64];
  const int tid = threadIdx.x;
  const int bid = blockIdx.x;
  const int xcd = bid & 7, ii = bid >> 3;
  int nt, mt, ks;
  if constexpr (NT == 16) {
    nt = xcd * 2 + (ii & 1); mt = (ii >> 1) & (MT - 1); ks = ii >> 4;
  } else {  // NT == 8
    nt = xcd; mt = ii & (MT - 1); ks = ii >> 3;
  }
  const long rowA0 = (long)mt * 256;
  const long rowB0 = (long)nt * 256;
  const long k0 = (long)ks * kslice;

  const int srow = tid >> 3;             // 0..63
  const int scolb = (tid & 7) << 4;      // LDS byte col 0..112
  const int gcolb = scolb ^ ((srow & 7) << 4);  // pre-swizzled source col
  const f16* gA = A + (rowA0 + srow) * (long)K + k0 + (gcolb >> 1);
  const f16* gB = Bw + (rowB0 + srow) * (long)K + k0 + (gcolb >> 1);

#define SGA(d, q, kt) async_copy16(gA + (kt) + (long)(q) * 64 * K, &sA[d][0] + (q) * 4096 + tid * 8)
#define SGB(d, q, kt) async_copy16(gB + (kt) + (long)(q) * 64 * K, &sB[d][0] + (q) * 4096 + tid * 8)

  const int lane = tid & 63;
  const int wave = tid >> 6;
  const int wr = wave >> 2;              // 0..1  (128-row half)
  const int wc = wave & 3;               // 0..3  (64-col quarter)
  const int frow = lane & 15;
  const int kb = (lane >> 4) << 4;
  const int rsw = (frow & 7) << 4;

  f32x4 acc[8][4] = {};
  f16x8 af[4][2], bf[4][2];

#define RDA(d, mh) do { _Pragma("unroll") for (int m_ = 0; m_ < 4; m_++) {                      \
    const int row_ = wr * 128 + (mh) * 64 + m_ * 16 + frow;                                     \
    af[m_][0] = *(const f16x8*)((const char*)&sA[d][0] + row_ * 128 + (kb ^ rsw));              \
    af[m_][1] = *(const f16x8*)((const char*)&sA[d][0] + row_ * 128 + ((64 + kb) ^ rsw)); } } while (0)
#define RDB(d) do { _Pragma("unroll") for (int n_ = 0; n_ < 4; n_++) {                          \
    const int row_ = wc * 64 + n_ * 16 + frow;                                                  \
    bf[n_][0] = *(const f16x8*)((const char*)&sB[d][0] + row_ * 128 + (kb ^ rsw));              \
    bf[n_][1] = *(const f16x8*)((const char*)&sB[d][0] + row_ * 128 + ((64 + kb) ^ rsw)); } } while (0)
#define QUAD(mh, nh) do { _Pragma("unroll") for (int m_ = 0; m_ < 4; m_++)                      \
    _Pragma("unroll") for (int n_ = 0; n_ < 2; n_++) {                                          \
      acc[(mh)*4+m_][(nh)*2+n_] = __builtin_amdgcn_mfma_f32_16x16x32_f16(af[m_][0], bf[(nh)*2+n_][0], acc[(mh)*4+m_][(nh)*2+n_], 0, 0, 0); \
      acc[(mh)*4+m_][(nh)*2+n_] = __builtin_amdgcn_mfma_f32_16x16x32_f16(af[m_][1], bf[(nh)*2+n_][1], acc[(mh)*4+m_][(nh)*2+n_], 0, 0, 0); } } while (0)
#define VMW8 asm volatile("s_waitcnt vmcnt(8)" ::: "memory")
#define VMW0 asm volatile("s_waitcnt vmcnt(0)" ::: "memory")
#define PRIO1 __builtin_amdgcn_s_setprio(1)
#define PRIO0 __builtin_amdgcn_s_setprio(0)

  // prologue: tile0 -> d0, tile1 -> d1
  SGA(0, 0, 0); SGA(0, 2, 0); SGB(0, 0, 0); SGB(0, 1, 0);
  SGA(0, 1, 0); SGA(0, 3, 0); SGB(0, 2, 0); SGB(0, 3, 0);
  SGA(1, 0, 64); SGA(1, 2, 64); SGB(1, 0, 64); SGB(1, 1, 64);
  SGA(1, 1, 64); SGA(1, 3, 64); SGB(1, 2, 64); SGB(1, 3, 64);

  for (int t = 0; t < LOOPN; ++t) {
    const long kt2 = (long)(t + 1) * 128;   // rel K offset of tile 2t+2
    // P0: compute d0 quad(0,0)
    VMW8; MEMPIN; RBAR; MEMPIN;
    RDA(0, 0); RDB(0);
    PRIO1; QUAD(0, 0); PRIO0;
    MEMPIN; RBAR; MEMPIN;
    // P1: stage tile(2t+2) A02,B01 -> d0
    SGA(0, 0, kt2); SGA(0, 2, kt2); SGB(0, 0, kt2); SGB(0, 1, kt2);
    QUAD(0, 1);
    // P2
    RDA(0, 1);
    QUAD(1, 0);
    MEMPIN; RBAR; MEMPIN;
    // P3: stage tile(2t+2) A13,B23 -> d0
    SGA(0, 1, kt2); SGA(0, 3, kt2); SGB(0, 2, kt2); SGB(0, 3, kt2);
    QUAD(1, 1);
    // P4: compute d1 quad(0,0)
    VMW8; MEMPIN; RBAR; MEMPIN;
    RDA(1, 0); RDB(1);
    PRIO1; QUAD(0, 0); PRIO0;
    MEMPIN; RBAR; MEMPIN;
    // P5: stage tile(2t+3) A02,B01 -> d1
    SGA(1, 0, kt2 + 64); SGA(1, 2, kt2 + 64); SGB(1, 0, kt2 + 64); SGB(1, 1, kt2 + 64);
    QUAD(0, 1);
    // P6
    RDA(1, 1);
    QUAD(1, 0);
    MEMPIN; RBAR; MEMPIN;
    // P7: stage tile(2t+3) A13,B23 -> d1
    SGA(1, 1, kt2 + 64); SGA(1, 3, kt2 + 64); SGB(1, 2, kt2 + 64); SGB(1, 3, kt2 + 64);
    QUAD(1, 1);
  }
  // peeled final iteration: last two tiles
  VMW8; MEMPIN; RBAR; MEMPIN;
  RDA(0, 0); RDB(0);
  PRIO1; QUAD(0, 0); QUAD(0, 1); PRIO0;
  RDA(0, 1);
  PRIO1; QUAD(1, 0); QUAD(1, 1); PRIO0;
  VMW0; MEMPIN; RBAR; MEMPIN;
  RDA(1, 0); RDB(1);
  PRIO1; QUAD(0, 0); QUAD(0, 1); PRIO0;
  RDA(1, 1);
  PRIO1; QUAD(1, 0); QUAD(1, 1); PRIO0;

  // epilogue: write f16 partial P[ks][2048][PLD]
  f16* Pp = P + (long)ks * 2048 * PLD;
#pragma unroll
  for (int mi = 0; mi < 8; mi++) {
    const long r0 = rowA0 + wr * 128 + (mi >> 2) * 64 + (mi & 3) * 16 + ((lane >> 4) << 2);
#pragma unroll
    for (int n = 0; n < 4; n++) {
      const long col = rowB0 + wc * 64 + n * 16 + (lane & 15);
#pragma unroll
      for (int r = 0; r < 4; r++)
        Pp[(r0 + r) * PLD + col] = (f16)acc[mi][n][r];
    }
  }
#undef SGA
#undef SGB
#undef RDA
#undef RDB
#undef QUAD
#undef VMW8
#undef VMW0
#undef PRIO1
#undef PRIO0
}

// ---------------- fixup body: C = relu(sum_s P_s + b) ----------------
template <int S>
DEVI void fix_body(const f16* __restrict__ P, const float* __restrict__ b,
                   f16* __restrict__ C, int N, int realN, int bix, int nblk)
{
  const long total = 2048L * N;
  const int mask = N - 1;
  const long stride = (long)nblk * 256 * 8;
  for (long i = ((long)bix * 256 + threadIdx.x) * 8; i < total; i += stride) {
    float s[8];
#pragma unroll
    for (int j = 0; j < 8; j++) s[j] = 0.f;
#pragma unroll
    for (int ps = 0; ps < S; ps++) {
      const f16x8 p = *(const f16x8*)(P + (long)ps * total + i);
#pragma unroll
      for (int j = 0; j < 8; j++) s[j] += (float)p[j];
    }
    const int col = (int)(i & mask);
    f16x8 o;
#pragma unroll
    for (int j = 0; j < 8; j++) {
      const int c = col + j;
      const float bb = (c < realN) ? b[c] : 0.f;
      o[j] = (f16)fmaxf(s[j] + bb, 0.f);
    }
    *(f16x8*)(C + i) = o;
  }
}

template <int S>
__global__ __launch_bounds__(256) void k_fixs(const f16* __restrict__ P, const float* __restrict__ b,
                                              f16* __restrict__ C, int N, int realN)
{
  fix_body<S>(P, b, C, N, realN, blockIdx.x, gridDim.x);
}

// merged: fc0 fixup (blocks 0..2047) + w1 convert (2048..2559) + w2 convert (2560..2815)
__global__ __launch_bounds__(256) void k_fixcvt(const f16* __restrict__ P, const float* __restrict__ b0,
                                                f16* __restrict__ h0,
                                                const float* __restrict__ w1, f16* __restrict__ w1f,
                                                const float* __restrict__ w2, f16* __restrict__ w2f)
{
  const int bx = blockIdx.x;
  if (bx < 2048)       fix_body<2>(P, b0, h0, 4096, 3968, bx, 2048);
  else if (bx < 2560)  cvt_body(w1, w1f, 1984, 3968, 2048, 4096, bx - 2048, 512);
  else                 cvt_body(w2, w2f, 992, 1984, 1024, 2048, bx - 2560, 256);
}

// ---------------- generic fp16 BT GEMM (128x128), 1D grid + XCD decode ----------------
// KS=1: C = act(A@B^T + bias). KS=2: split-K, writes f16 partials to C (=P), no bias/act.
template <int RELU, int KS>
__global__ __launch_bounds__(256, 2) void k_gemm_f16(
    const f16* __restrict__ A, const f16* __restrict__ B,
    const float* __restrict__ bias, f16* __restrict__ C,
    int N, int K, int realN)
{
  __shared__ f16 sA[128 * 64];
  __shared__ f16 sB[128 * 64];
  const int tid = threadIdx.x;
  const int lane = tid & 63;
  const int wave = tid >> 6;
  const int wr = wave >> 1, wc = wave & 1;
  const int bid = blockIdx.x;
  const int xcd = bid & 7, idx = bid >> 3;
  const long rowA0 = (long)(xcd * 2 + (idx & 1)) * 128;
  long rowB0;
  int ks;
  if constexpr (KS == 2) {
    rowB0 = (long)((idx >> 1) & 7) * 128;
    ks = idx >> 4;
  } else {
    rowB0 = (long)(idx >> 1) * 128;
    ks = 0;
  }
  const int kslice = K / KS;
  const long k0 = (long)ks * kslice;

  const int srow = tid >> 3;
  const int scolb = (tid & 7) << 4;
  const int gcolb = scolb ^ ((srow & 7) << 4);
  const f16* gA = A + (rowA0 + srow) * (long)K + k0 + (gcolb >> 1);
  const f16* gB = B + (rowB0 + srow) * (long)K + k0 + (gcolb >> 1);
  f16* lA = sA + srow * 64 + (scolb >> 1);
  f16* lB = sB + srow * 64 + (scolb >> 1);
  const long rstep = 32L * K;

  const int frow = lane & 15;
  const int kb = (lane >> 4) << 4;
  const int rswz = (lane & 7) << 4;

  f32x4 acc[4][4] = {};

  for (int kt = 0; kt < kslice; kt += 64) {
#pragma unroll
    for (int i = 0; i < 4; i++) {
      async_copy16(gA + kt + i * rstep, lA + i * 2048);
      async_copy16(gB + kt + i * rstep, lB + i * 2048);
    }
    __syncthreads();
#pragma unroll
    for (int kk = 0; kk < 2; kk++) {
      f16x8 af[4], bf[4];
#pragma unroll
      for (int m = 0; m < 4; m++) {
        const int row = wr * 64 + m * 16 + frow;
        af[m] = *(const f16x8*)((const char*)sA + row * 128 + ((kk * 64 + kb) ^ rswz));
      }
#pragma unroll
      for (int n = 0; n < 4; n++) {
        const int row = wc * 64 + n * 16 + frow;
        bf[n] = *(const f16x8*)((const char*)sB + row * 128 + ((kk * 64 + kb) ^ rswz));
      }
#pragma unroll
      for (int m = 0; m < 4; m++)
#pragma unroll
        for (int n = 0; n < 4; n++)
          acc[m][n] = __builtin_amdgcn_mfma_f32_16x16x32_f16(af[m], bf[n], acc[m][n], 0, 0, 0);
    }
    __syncthreads();
  }

  const int crow = wr * 64 + ((lane >> 4) << 2);
  const int ccol = wc * 64 + (lane & 15);
  if constexpr (KS == 1) {
#pragma unroll
    for (int n = 0; n < 4; n++) {
      const int col = (int)rowB0 + ccol + n * 16;
      const float bb = (col < realN) ? bias[col] : 0.f;
#pragma unroll
      for (int m = 0; m < 4; m++) {
        const long gr = rowA0 + crow + m * 16;
#pragma unroll
        for (int r = 0; r < 4; r++) {
          float v = acc[m][n][r] + bb;
          if (RELU) v = fmaxf(v, 0.f);
          C[(gr + r) * N + col] = (f16)v;
        }
      }
    }
  } else {
    f16* Pp = C + (long)ks * 2048 * N;
#pragma unroll
    for (int n = 0; n < 4; n++) {
      const long col = rowB0 + ccol + n * 16;
#pragma unroll
      for (int m = 0; m < 4; m++) {
        const long gr = rowA0 + crow + m * 16;
#pragma unroll
        for (int r = 0; r < 4; r++)
          Pp[(gr + r) * N + col] = (f16)acc[m][n][r];
      }
    }
  }
}

// ---------------- fc3 fused with fc2 fixup: out = relu(P0+P1+b2)[:, :992] @ w3^T + b3 ----------------
__global__ __launch_bounds__(256) void k_fc3p(const f16* __restrict__ P, const float* __restrict__ b2,
                                              const float* __restrict__ W, const float* __restrict__ b,
                                              float* __restrict__ out)
{
  const int row = blockIdx.x * 4 + (threadIdx.x >> 6);
  const int lane = threadIdx.x & 63;
  const f16* p0 = P + (long)row * 1024;
  const f16* p1 = P + 2048L * 1024 + (long)row * 1024;
  float a0 = 0.f, a1 = 0.f;
  for (int k = lane; k < 992; k += 64) {
    const float v = fmaxf((float)p0[k] + (float)p1[k] + b2[k], 0.f);
    a0 += v * W[k];
    a1 += v * W[992 + k];
  }
  for (int off = 32; off; off >>= 1) {
    a0 += __shfl_down(a0, off);
    a1 += __shfl_down(a1, off);
  }
  if (lane == 0) {
    out[row * 2 + 0] = a0 + b[0];
    out[row * 2 + 1] = a1 + b[1];
  }
}

extern "C" void kernel_launch(void* const* d_in, const int* in_sizes, int n_in,
                              void* d_out, int out_size, void* d_ws, size_t ws_size,
                              hipStream_t stream)
{
  const float* x    = (const float*)d_in[0];
  const float* ew   = (const float*)d_in[1];
  const float* bng  = (const float*)d_in[2];
  const float* bnb  = (const float*)d_in[3];
  const float* linw = (const float*)d_in[4];
  const float* linb = (const float*)d_in[5];
  const float* w0   = (const float*)d_in[6];
  const float* b0   = (const float*)d_in[7];
  const float* w1   = (const float*)d_in[8];
  const float* b1   = (const float*)d_in[9];
  const float* w2   = (const float*)d_in[10];
  const float* b2   = (const float*)d_in[11];
  const float* w3   = (const float*)d_in[12];
  const float* b3   = (const float*)d_in[13];
  float* out = (float*)d_out;
  char* ws = (char*)d_ws;

  // layout (bytes)
  constexpr size_t oA2  = 0;                         // 16384
  constexpr size_t oSS  = 16384;                     // 4096
  constexpr size_t oB1P = 20480;                     // 512
  constexpr size_t oW1H = 20992;                     // 131072, end 152064
  constexpr size_t oP   = 152064;                    // 33554432 (fc0: 2x2048x4096; fc1: 4x2048x2048; fc2: 2x2048x1024 f16)
  constexpr size_t oACC = oP;                        // bn partials (1 MiB), dead before fc0
  constexpr size_t oZ   = 33706496;                  // 32505856, end 66212352
  constexpr size_t oW0H = 66212352;                  // 4096*7936 f16 = 65011712, end 131224064
  constexpr size_t WS_NEED = 131224064;
  // post-fc0 aliases (Z and w0h dead after fc0):
  constexpr size_t oH0  = oZ;                        // 2048*4096 f16 = 16777216
  constexpr size_t oW1F = oZ + 16777216;             // 16777216, end 67260928
  constexpr size_t oH1  = 67260928;                  // 8388608
  constexpr size_t oW2F = 75649536;                  // 4194304
  if (ws_size < WS_NEED) return;

  float* A2  = (float*)(ws + oA2);
  float* acc = (float*)(ws + oACC);
  float* ssb = (float*)(ws + oSS);
  float* b1p = (float*)(ws + oB1P);
  f16* w1h = (f16*)(ws + oW1H);
  f16* P   = (f16*)(ws + oP);
  f16* Z   = (f16*)(ws + oZ);
  f16* w0h = (f16*)(ws + oW0H);
  f16* h0  = (f16*)(ws + oH0);
  f16* w1f = (f16*)(ws + oW1F);
  f16* h1  = (f16*)(ws + oH1);
  f16* w2f = (f16*)(ws + oW2F);

  // 1. BN partial stats (256 blocks) + adjacency/A2 (block 256)
  k_bnadj<<<257, 1024, 0, stream>>>(x, acc, ew, A2);
  // 2. finalize BN scale/shift
  k_bnfin<<<1, 512, 0, stream>>>(acc, bng, bnb, ssb);
  // 3. fold BN into lin_w
  k_foldw1<<<128, 256, 0, stream>>>(linw, ssb, w1h, b1p);
  // 4. fused lin-GEMM + 2-hop propagation -> Z  (+ w0 convert in blocks 1024..2047)
  k_linprop_cvt<<<2048, 256, 0, stream>>>(x, w1h, A2, b1p, linb, Z, w0, w0h);
  // 5. fc0: [2048,7936] x [4096(3968),7936]^T -> f16 partials (split-K=2)
  k_fc8<30, 8, 16, 2><<<256, 512, 0, stream>>>(Z, w0h, P, 7936, 3968, 4096);
  // 6. fc0 fixup + w1/w2 converts (merged)
  k_fixcvt<<<2816, 256, 0, stream>>>(P, b0, h0, w1, w1f, w2, w2f);
  // 7. fc1: [2048,4096] x [2048(1984),4096]^T -> f16 partials (split-K=4)
  k_fc8<7, 8, 8, 4><<<256, 512, 0, stream>>>(h0, w1f, P, 4096, 1024, 2048);
  // 8. fc1 fixup
  k_fixs<4><<<1024, 256, 0, stream>>>(P, b1, h1, 2048, 1984);
  // 9. fc2: [2048,2048] x [1024(992),2048]^T -> split-K=2 partials (256 blocks)
  k_gemm_f16<1, 2><<<256, 256, 0, stream>>>(h1, w2f, b2, P, 1024, 2048, 992);
  // 10. fc3 fused with fc2 fixup
  k_fc3p<<<512, 256, 0, stream>>>(P, b2, w3, b3, out);
}